// Round 3
// baseline (285.844 us; speedup 1.0000x reference)
//
#include <hip/hip_runtime.h>
#include <cstddef>

#define B_  16384
#define F_  2048
#define T_  64
#define C_  32
#define H_  24
#define HH_ 48
#define THR 256
#define ROWS_BLK 1024
#define NCHUNK (B_ / ROWS_BLK)   // 16
#define GRID_  (T_ * NCHUNK)     // 1024 blocks
#define SL_STRIDE 72             // shorts per S_lds row (144 B: 16B-aligned, 2-way banks)
#define MAGIC 0x13579BDF

typedef __attribute__((ext_vector_type(8))) short  short8;   // 8 bf16 (4 VGPRs)
typedef __attribute__((ext_vector_type(4))) float  floatx4;

__device__ __forceinline__ short f2bf(float f) {   // fp32 -> bf16 bits, RNE
    union { float f; unsigned u; } v; v.f = f;
    unsigned r = v.u + 0x7FFFu + ((v.u >> 16) & 1u);
    return (short)(r >> 16);
}

// ---------------------------------------------------------------------------
// err_row = s^T (G-2I) s + d.s + k0 + sum_c x_c (x_c - 2 w2_c)
// with d = 2 W^T w2 (hb term verified spurious), k0 = |w2|^2, w2 = vb + W hb.
// Single dispatch: block 0 spin-waits on per-block MAGIC flags (workspace is
// re-poisoned every iteration, so flags start != MAGIC) and computes the head
// in-kernel -- removes the second dispatch + its gap.
// ---------------------------------------------------------------------------
__global__ __launch_bounds__(THR, 4) void kitnet_main(
    const float* __restrict__ x, const int* __restrict__ clusters,
    const float* __restrict__ Wt, const float* __restrict__ hb,
    const float* __restrict__ vb, const float* __restrict__ Wh,
    const float* __restrict__ hbh, const float* __restrict__ vbh,
    float* __restrict__ partial, int* __restrict__ flags,
    float* __restrict__ out)
{
    __shared__ __align__(16) float WL[C_ * H_];   // W[c][j]
    __shared__ __align__(16) float GL[H_ * H_];   // G' = W^T W - 2I
    __shared__ __align__(16) float w2L[C_];
    __shared__ __align__(16) float dL[H_];
    __shared__ __align__(16) float hbL[H_];
    __shared__ float k0L;
    __shared__ int   colsL[C_];
    __shared__ int   contigS;
    __shared__ float wsum[4];
    __shared__ __align__(16) short Sl[4 * 16 * SL_STRIDE];  // per-wave S tiles
    __shared__ float tl[T_];      // head: tails
    __shared__ float hhL[HH_];    // head: hidden

    const int tid   = threadIdx.x;
    const int t     = blockIdx.x >> 4;            // chunk-fastest: XCD = chunk%8
    const int chunk = blockIdx.x & (NCHUNK - 1);
    const int b0    = chunk * ROWS_BLK;

    // ---- phase 1: stage W, hb, cols ----
    for (int i = tid; i < C_ * H_; i += THR) WL[i] = Wt[t * C_ * H_ + i];
    if (tid < H_) hbL[tid] = hb[t * H_ + tid];
    if (tid < C_) colsL[tid] = clusters[t * C_ + tid];
    __syncthreads();

    // ---- phase 2: w2, contiguity ----
    if (tid < C_) {
        float a = vb[t * C_ + tid];
        #pragma unroll
        for (int j = 0; j < H_; ++j) a += WL[tid * H_ + j] * hbL[j];
        w2L[tid] = a;
    }
    if (tid == 0) {
        int ok = (colsL[0] & 3) == 0;
        for (int c = 1; c < C_; ++c) ok &= (colsL[c] == colsL[0] + c);
        contigS = ok;
    }
    __syncthreads();

    // ---- phase 3: G', d, k0 ----
    for (int idx = tid; idx < H_ * H_; idx += THR) {
        const int i = idx / H_, j = idx - i * H_;
        float a = 0.f;
        #pragma unroll
        for (int c = 0; c < C_; ++c) a += WL[c * H_ + i] * WL[c * H_ + j];
        GL[idx] = (i == j) ? a - 2.f : a;
    }
    if (tid < H_) {
        float a = 0.f;
        #pragma unroll
        for (int c = 0; c < C_; ++c) a += w2L[c] * WL[c * H_ + tid];
        dL[tid] = 2.f * a;                       // d = 2 W^T w2 (no hb term)
    }
    if (tid == THR - 1) {
        float a = 0.f;
        for (int c = 0; c < C_; ++c) a += w2L[c] * w2L[c];
        k0L = a;
    }
    __syncthreads();

    const int lane = tid & 63;
    const int wid  = tid >> 6;
    const int m    = lane & 15;    // A row / B-D col
    const int quad = lane >> 4;    // k-slice

    // ---- per-wave constant fragments (built once, reused for 16 groups) ----
    short8 bw0, bw1, gg0, gg1;
    float  m2w[8];                 // -2 * w2  (stats as pure FMA)
    #pragma unroll
    for (int j = 0; j < 8; ++j) {
        const int k = quad * 8 + j;
        bw0[j] = f2bf(WL[k * H_ + m]);                                 // W[c][n]
        bw1[j] = (m < 8) ? f2bf(WL[k * H_ + 16 + m]) : (short)0;       // n=16..23
        gg0[j] = (k < H_) ? f2bf(GL[k * H_ + m]) : (short)0;           // G'[j][i]
        gg1[j] = (k < H_ && m < 8) ? f2bf(GL[k * H_ + 16 + m]) : (short)0;
        m2w[j] = -2.f * w2L[k];
    }
    const float d0 = dL[m];
    const float d1 = (m < 8) ? dL[16 + m] : 0.f;

    short* sl = &Sl[wid * 16 * SL_STRIDE];
    const int contig = contigS;
    const int col0   = colsL[0];
    float err = 0.f;

#define PROCESS16(X0, X1, X2, X3, X4, X5, X6, X7)                             \
    {                                                                         \
        const float xv_[8] = {X0, X1, X2, X3, X4, X5, X6, X7};                \
        short8 af;                                                            \
        _Pragma("unroll")                                                     \
        for (int j = 0; j < 8; ++j) {                                         \
            err += xv_[j] * xv_[j] + xv_[j] * m2w[j];                         \
            af[j] = f2bf(xv_[j]);                                             \
        }                                                                     \
        const floatx4 z_ = {0.f, 0.f, 0.f, 0.f};                              \
        floatx4 S0 = __builtin_amdgcn_mfma_f32_16x16x32_bf16(af, bw0, z_, 0, 0, 0); \
        floatx4 S1 = __builtin_amdgcn_mfma_f32_16x16x32_bf16(af, bw1, z_, 0, 0, 0); \
        _Pragma("unroll")                                                     \
        for (int r = 0; r < 4; ++r) {                                         \
            sl[(quad * 4 + r) * SL_STRIDE + m]      = f2bf(S0[r]);            \
            sl[(quad * 4 + r) * SL_STRIDE + 16 + m] = f2bf(S1[r]);            \
        }                                                                     \
        short8 sf = *(const short8*)&sl[m * SL_STRIDE + quad * 8];            \
        floatx4 Q0 = __builtin_amdgcn_mfma_f32_16x16x32_bf16(sf, gg0, z_, 0, 0, 0); \
        floatx4 Q1 = __builtin_amdgcn_mfma_f32_16x16x32_bf16(sf, gg1, z_, 0, 0, 0); \
        _Pragma("unroll")                                                     \
        for (int r = 0; r < 4; ++r)                                           \
            err += (Q0[r] + d0) * S0[r] + (Q1[r] + d1) * S1[r];               \
    }

    if (contig) {
        // lane loads 32 B contiguous of its row; prefetch depth 2 (4 KB/wave in flight)
        const float* xbase = x + (size_t)(b0 + wid * 256 + m) * F_ + col0 + quad * 8;
        float4 pa0 = *(const float4*)xbase;
        float4 pb0 = *(const float4*)(xbase + 4);
        float4 pa1 = *(const float4*)(xbase + (size_t)16 * F_);
        float4 pb1 = *(const float4*)(xbase + (size_t)16 * F_ + 4);
        for (int g = 0; g < 16; ++g) {
            const float4 xa = pa0, xb = pb0;
            pa0 = pa1; pb0 = pb1;
            if (g < 14) {
                const float* nx = xbase + (size_t)(g + 2) * 16 * F_;
                pa1 = *(const float4*)nx;
                pb1 = *(const float4*)(nx + 4);
            }
            PROCESS16(xa.x, xa.y, xa.z, xa.w, xb.x, xb.y, xb.z, xb.w)
        }
    } else {
        for (int g = 0; g < 16; ++g) {
            const size_t rb = (size_t)(b0 + wid * 256 + g * 16 + m) * F_;
            float xf[8];
            #pragma unroll
            for (int j = 0; j < 8; ++j) xf[j] = x[rb + colsL[quad * 8 + j]];
            PROCESS16(xf[0], xf[1], xf[2], xf[3], xf[4], xf[5], xf[6], xf[7])
        }
    }
#undef PROCESS16

    // ---- reduce: wave shuffle -> block -> one partial + flag per block ----
    #pragma unroll
    for (int off = 32; off > 0; off >>= 1) err += __shfl_down(err, off, 64);
    if (lane == 0) wsum[wid] = err;
    __syncthreads();
    if (tid == 0) {
        partial[blockIdx.x] = wsum[0] + wsum[1] + wsum[2] + wsum[3]
                            + (float)ROWS_BLK * k0L;
        __threadfence();
        __hip_atomic_store(&flags[blockIdx.x], MAGIC,
                           __ATOMIC_RELEASE, __HIP_MEMORY_SCOPE_AGENT);
    }

    // ---- head (block 0 only): wait for all blocks, then tiny matmuls ----
    if (blockIdx.x == 0) {
        for (int i = tid; i < GRID_; i += THR) {
            while (__hip_atomic_load(&flags[i], __ATOMIC_ACQUIRE,
                                     __HIP_MEMORY_SCOPE_AGENT) != MAGIC)
                __builtin_amdgcn_s_sleep(8);
        }
        __syncthreads();

        if (tid < T_) {
            float sse = 0.f;
            #pragma unroll
            for (int c = 0; c < NCHUNK; ++c)
                sse += __hip_atomic_load(&partial[tid * NCHUNK + c],
                                         __ATOMIC_RELAXED, __HIP_MEMORY_SCOPE_AGENT);
            const float tail = 0.5f * logf(sse * (1.0f / ((float)B_ * (float)C_)));
            tl[tid] = tail;
            out[T_ + tid] = tail;
        }
        __syncthreads();

        if (tid < HH_) {
            float acc = hbh[tid];
            #pragma unroll 8
            for (int tt = 0; tt < T_; ++tt) acc += tl[tt] * Wh[tt * HH_ + tid];
            hhL[tid] = acc;
        }
        __syncthreads();

        if (tid < T_) {
            float ho = vbh[tid];
            #pragma unroll 8
            for (int j = 0; j < HH_; ++j) ho += hhL[j] * Wh[tid * HH_ + j];
            out[tid] = ho;
        }
    }
}

extern "C" void kernel_launch(void* const* d_in, const int* in_sizes, int n_in,
                              void* d_out, int out_size, void* d_ws, size_t ws_size,
                              hipStream_t stream)
{
    const float* x        = (const float*)d_in[0];
    const int*   clusters = (const int*)  d_in[1];
    const float* Wt       = (const float*)d_in[2];
    const float* hb       = (const float*)d_in[3];
    const float* vb       = (const float*)d_in[4];
    const float* Wh       = (const float*)d_in[5];
    const float* hbh      = (const float*)d_in[6];
    const float* vbh      = (const float*)d_in[7];
    float* out     = (float*)d_out;
    float* partial = (float*)d_ws;            // GRID_ floats, every slot written
    int*   flags   = (int*)d_ws + GRID_;      // GRID_ ints, poisoned (!= MAGIC) each call

    kitnet_main<<<dim3(GRID_), dim3(THR), 0, stream>>>(
        x, clusters, Wt, hb, vb, Wh, hbh, vbh, partial, flags, out);
}

// Round 5
// 237.908 us; speedup vs baseline: 1.2015x; 1.2015x over previous
//
#include <hip/hip_runtime.h>
#include <cstddef>

#define B_  16384
#define F_  2048
#define T_  64
#define C_  32
#define H_  24
#define HH_ 48
#define THR 256
#define ROWS_BLK 1024
#define NCHUNK (B_ / ROWS_BLK)   // 16
#define GRID_  (T_ * NCHUNK)     // 1024 blocks
#define SL_STRIDE 72             // shorts per S_lds row (144 B: 16B-aligned, 2-way banks)

typedef __attribute__((ext_vector_type(8))) short  short8;   // 8 bf16 (4 VGPRs)
typedef __attribute__((ext_vector_type(4))) float  floatx4;

__device__ __forceinline__ short f2bf(float f) {   // fp32 -> bf16 bits, RNE
    union { float f; unsigned u; } v; v.f = f;
    unsigned r = v.u + 0x7FFFu + ((v.u >> 16) & 1u);
    return (short)(r >> 16);
}

// ---------------------------------------------------------------------------
// err_row = s^T (G-2I) s + d.s + k0 + sum_c x_c (x_c - 2 w2_c)
// with d = 2 W^T w2 (verified), k0 = |w2|^2, w2 = vb + W hb.
// R3 post-mortem: latency-bound (L3-warm iteration equally slow, all pipes
// idle). This version: R0's proven 2-dispatch structure + TWO independent
// row-group chains per iteration (2x outstanding loads, 2 LDS/MFMA chains).
// ---------------------------------------------------------------------------
__global__ __launch_bounds__(THR) void kitnet_main(
    const float* __restrict__ x, const int* __restrict__ clusters,
    const float* __restrict__ Wt, const float* __restrict__ hb,
    const float* __restrict__ vb, float* __restrict__ partial)
{
    __shared__ __align__(16) float WL[C_ * H_];   // W[c][j]
    __shared__ __align__(16) float GL[H_ * H_];   // G' = W^T W - 2I
    __shared__ __align__(16) float w2L[C_];
    __shared__ __align__(16) float dL[H_];
    __shared__ __align__(16) float hbL[H_];
    __shared__ float k0L;
    __shared__ int   colsL[C_];
    __shared__ int   contigS;
    __shared__ float wsum[4];
    __shared__ __align__(16) short Sl[8 * 16 * SL_STRIDE];  // 2 chain slots / wave

    const int tid   = threadIdx.x;
    const int t     = blockIdx.x >> 4;            // chunk-fastest: XCD = chunk%8
    const int chunk = blockIdx.x & (NCHUNK - 1);
    const int b0    = chunk * ROWS_BLK;

    // ---- phase 1: stage W, hb, cols ----
    for (int i = tid; i < C_ * H_; i += THR) WL[i] = Wt[t * C_ * H_ + i];
    if (tid < H_) hbL[tid] = hb[t * H_ + tid];
    if (tid < C_) colsL[tid] = clusters[t * C_ + tid];
    __syncthreads();

    // ---- phase 2: w2, contiguity ----
    if (tid < C_) {
        float a = vb[t * C_ + tid];
        #pragma unroll
        for (int j = 0; j < H_; ++j) a += WL[tid * H_ + j] * hbL[j];
        w2L[tid] = a;
    }
    if (tid == 0) {
        int ok = (colsL[0] & 3) == 0;
        for (int c = 1; c < C_; ++c) ok &= (colsL[c] == colsL[0] + c);
        contigS = ok;
    }
    __syncthreads();

    // ---- phase 3: G', d, k0 ----
    for (int idx = tid; idx < H_ * H_; idx += THR) {
        const int i = idx / H_, j = idx - i * H_;
        float a = 0.f;
        #pragma unroll
        for (int c = 0; c < C_; ++c) a += WL[c * H_ + i] * WL[c * H_ + j];
        GL[idx] = (i == j) ? a - 2.f : a;
    }
    if (tid < H_) {
        float a = 0.f;
        #pragma unroll
        for (int c = 0; c < C_; ++c) a += w2L[c] * WL[c * H_ + tid];
        dL[tid] = 2.f * a;                       // d = 2 W^T w2 (no hb term)
    }
    if (tid == THR - 1) {
        float a = 0.f;
        for (int c = 0; c < C_; ++c) a += w2L[c] * w2L[c];
        k0L = a;
    }
    __syncthreads();

    const int lane = tid & 63;
    const int wid  = tid >> 6;
    const int m    = lane & 15;    // A row / B-D col
    const int quad = lane >> 4;    // k-slice

    // ---- per-wave constant fragments ----
    short8 bw0, bw1, gg0, gg1;
    float  m2w[8];                 // -2 * w2
    #pragma unroll
    for (int j = 0; j < 8; ++j) {
        const int k = quad * 8 + j;
        bw0[j] = f2bf(WL[k * H_ + m]);                                 // W[c][n]
        bw1[j] = (m < 8) ? f2bf(WL[k * H_ + 16 + m]) : (short)0;       // n=16..23
        gg0[j] = (k < H_) ? f2bf(GL[k * H_ + m]) : (short)0;           // G'[j][i]
        gg1[j] = (k < H_ && m < 8) ? f2bf(GL[k * H_ + 16 + m]) : (short)0;
        m2w[j] = -2.f * w2L[k];
    }
    const float d0 = dL[m];
    const float d1 = (m < 8) ? dL[16 + m] : 0.f;

    short* sl0 = &Sl[(wid * 2 + 0) * 16 * SL_STRIDE];
    short* sl1 = &Sl[(wid * 2 + 1) * 16 * SL_STRIDE];
    const int contig = contigS;
    const int col0   = colsL[0];
    float err = 0.f, errB = 0.f;

// one 16-row group through S = X.W -> LDS hop -> Q = S.G' -> err
#define PROCESS16(XA, XB, SLP, ERR)                                           \
    {                                                                         \
        const float xv_[8] = {XA.x, XA.y, XA.z, XA.w, XB.x, XB.y, XB.z, XB.w};\
        short8 af;                                                            \
        _Pragma("unroll")                                                     \
        for (int j = 0; j < 8; ++j) {                                         \
            ERR += xv_[j] * xv_[j] + xv_[j] * m2w[j];                         \
            af[j] = f2bf(xv_[j]);                                             \
        }                                                                     \
        const floatx4 z_ = {0.f, 0.f, 0.f, 0.f};                              \
        floatx4 S0 = __builtin_amdgcn_mfma_f32_16x16x32_bf16(af, bw0, z_, 0, 0, 0); \
        floatx4 S1 = __builtin_amdgcn_mfma_f32_16x16x32_bf16(af, bw1, z_, 0, 0, 0); \
        _Pragma("unroll")                                                     \
        for (int r = 0; r < 4; ++r) {                                         \
            (SLP)[(quad * 4 + r) * SL_STRIDE + m]      = f2bf(S0[r]);         \
            (SLP)[(quad * 4 + r) * SL_STRIDE + 16 + m] = f2bf(S1[r]);         \
        }                                                                     \
        short8 sf = *(const short8*)&(SLP)[m * SL_STRIDE + quad * 8];         \
        floatx4 Q0 = __builtin_amdgcn_mfma_f32_16x16x32_bf16(sf, gg0, z_, 0, 0, 0); \
        floatx4 Q1 = __builtin_amdgcn_mfma_f32_16x16x32_bf16(sf, gg1, z_, 0, 0, 0); \
        _Pragma("unroll")                                                     \
        for (int r = 0; r < 4; ++r)                                           \
            ERR += (Q0[r] + d0) * S0[r] + (Q1[r] + d1) * S1[r];               \
    }

    if (contig) {
        // lane covers 32 B of its row; 2 groups/iter as independent chains,
        // next-pair loads issued before compute (8 KB in flight per wave)
        const float* xbase = x + (size_t)(b0 + wid * 256 + m) * F_ + col0 + quad * 8;
        float4 a0 = *(const float4*)xbase;
        float4 c0 = *(const float4*)(xbase + 4);
        float4 a1 = *(const float4*)(xbase + (size_t)16 * F_);
        float4 c1 = *(const float4*)(xbase + (size_t)16 * F_ + 4);
        for (int gp = 0; gp < 8; ++gp) {
            const float4 xa0 = a0, xc0 = c0, xa1 = a1, xc1 = c1;
            if (gp < 7) {
                const float* nx = xbase + (size_t)(2 * gp + 2) * 16 * F_;
                a0 = *(const float4*)nx;
                c0 = *(const float4*)(nx + 4);
                a1 = *(const float4*)(nx + (size_t)16 * F_);
                c1 = *(const float4*)(nx + (size_t)16 * F_ + 4);
            }
            PROCESS16(xa0, xc0, sl0, err)
            PROCESS16(xa1, xc1, sl1, errB)
        }
    } else {
        for (int g = 0; g < 16; ++g) {
            const size_t rb = (size_t)(b0 + wid * 256 + g * 16 + m) * F_;
            float xf[8];
            #pragma unroll
            for (int j = 0; j < 8; ++j) xf[j] = x[rb + colsL[quad * 8 + j]];
            float4 xa = {xf[0], xf[1], xf[2], xf[3]};
            float4 xc = {xf[4], xf[5], xf[6], xf[7]};
            PROCESS16(xa, xc, sl0, err)
        }
    }
#undef PROCESS16
    err += errB;

    // ---- reduce: wave shuffle -> block -> one partial per block ----
    #pragma unroll
    for (int off = 32; off > 0; off >>= 1) err += __shfl_down(err, off, 64);
    if (lane == 0) wsum[wid] = err;
    __syncthreads();
    if (tid == 0)
        partial[blockIdx.x] = wsum[0] + wsum[1] + wsum[2] + wsum[3]
                            + (float)ROWS_BLK * k0L;
}

// ---------------------------------------------------------------------------
// Kernel B: sum partials -> tails -> 2 tiny head matmuls. One wave.
// d_out = [ head_out (64) | tails (64) ]
// ---------------------------------------------------------------------------
__global__ __launch_bounds__(64) void kitnet_head(
    const float* __restrict__ partial, const float* __restrict__ Wh,
    const float* __restrict__ hbh, const float* __restrict__ vbh,
    float* __restrict__ out)
{
    __shared__ float tl[T_];
    __shared__ float hhL[HH_];
    const int tid = threadIdx.x;

    float sse = 0.f;
    #pragma unroll
    for (int c = 0; c < NCHUNK; ++c) sse += partial[tid * NCHUNK + c];

    const float tail = 0.5f * logf(sse * (1.0f / ((float)B_ * (float)C_)));
    tl[tid] = tail;
    out[T_ + tid] = tail;
    __syncthreads();

    if (tid < HH_) {
        float acc = hbh[tid];
        #pragma unroll 8
        for (int t = 0; t < T_; ++t) acc += tl[t] * Wh[t * HH_ + tid];
        hhL[tid] = acc;
    }
    __syncthreads();

    float ho = vbh[tid];
    #pragma unroll 8
    for (int j = 0; j < HH_; ++j) ho += hhL[j] * Wh[tid * HH_ + j];
    out[tid] = ho;
}

extern "C" void kernel_launch(void* const* d_in, const int* in_sizes, int n_in,
                              void* d_out, int out_size, void* d_ws, size_t ws_size,
                              hipStream_t stream)
{
    const float* x        = (const float*)d_in[0];
    const int*   clusters = (const int*)  d_in[1];
    const float* Wt       = (const float*)d_in[2];
    const float* hb       = (const float*)d_in[3];
    const float* vb       = (const float*)d_in[4];
    const float* Wh       = (const float*)d_in[5];
    const float* hbh      = (const float*)d_in[6];
    const float* vbh      = (const float*)d_in[7];
    float* out     = (float*)d_out;
    float* partial = (float*)d_ws;   // T_*NCHUNK floats; every slot written each call

    kitnet_main<<<dim3(GRID_), dim3(THR), 0, stream>>>(x, clusters, Wt, hb, vb, partial);
    kitnet_head<<<dim3(1), dim3(64), 0, stream>>>(partial, Wh, hbh, vbh, out);
}

// Round 8
// 215.025 us; speedup vs baseline: 1.3293x; 1.1064x over previous
//
#include <hip/hip_runtime.h>
#include <cstddef>

#define B_  16384
#define F_  2048
#define T_  64
#define C_  32
#define H_  24
#define HH_ 48
#define THR 256
#define ROWS_BLK 512
#define NCHUNK (B_ / ROWS_BLK)   // 32
#define GRID_  (T_ * NCHUNK)     // 2048 blocks

typedef __attribute__((ext_vector_type(8))) short  short8;   // 8 bf16 (4 VGPRs)
typedef __attribute__((ext_vector_type(4))) float  floatx4;
typedef __attribute__((ext_vector_type(4))) int    intx4;

__device__ __forceinline__ short f2bf(float f) {   // fp32 -> bf16 bits, RNE
    union { float f; unsigned u; } v; v.f = f;
    unsigned r = v.u + 0x7FFFu + ((v.u >> 16) & 1u);
    return (short)(r >> 16);
}

__device__ __forceinline__ int pk2bf(float lo, float hi) {  // [hi:lo] bf16, RNE, pure int
    union { float f; unsigned u; } a, b;
    a.f = lo; b.f = hi;
    unsigned ra = (a.u + 0x7FFFu + ((a.u >> 16) & 1u)) >> 16;
    unsigned rb = (b.u + 0x7FFFu + ((b.u >> 16) & 1u)) & 0xFFFF0000u;
    return (int)(ra | rb);
}

// ---------------------------------------------------------------------------
// Per-row err = s^T(G-2I)s + d.s + k0 + sum_c x_c(x_c - 2 w2_c),
// d = 2 W^T w2 (verified), k0 = |w2|^2, w2 = vb + W hb.
// Trace identity: sum_rows s^T G' s = sum_ij G'_ij (S^T S)_ij.
// M = S^T S accumulated by MFMA over 32-row stacks (2 groups, K=32).
// D->A hop needs NO shuffles: M is invariant to row permutation of the
// stack; choose the permutation where each lane's A/B fragment is its OWN
// packed MFMA outputs {pA0,pA1,pB0,pB1}. Valid under any consistent HW
// slot->k bijection (R0-verified layouts). R7 post-mortem: the only fragile
// piece was cvt_pk_bf16 on the X-fragment (must align elementwise with bw);
// now ALL packing is explicit integer RNE (pk2bf) / elementwise f2bf --
// zero dependence on cvt_pk ISA semantics. Loop: ZERO LDS ops, ZERO shuffles.
// ---------------------------------------------------------------------------
__global__ __launch_bounds__(THR, 6) void kitnet_main(
    const float* __restrict__ x, const int* __restrict__ clusters,
    const float* __restrict__ Wt, const float* __restrict__ hb,
    const float* __restrict__ vb, float* __restrict__ partial)
{
    __shared__ __align__(16) float WL[C_ * H_];   // W[c][j]
    __shared__ __align__(16) float GL[H_ * H_];   // G' = W^T W - 2I (f32, epilogue)
    __shared__ __align__(16) float w2L[C_];
    __shared__ __align__(16) float dL[H_];
    __shared__ __align__(16) float hbL[H_];
    __shared__ float k0L;
    __shared__ int   colsL[C_];
    __shared__ int   contigS;
    __shared__ float wsum[4];

    const int tid   = threadIdx.x;
    const int t     = blockIdx.x >> 5;            // chunk-fastest: XCD = chunk%8
    const int chunk = blockIdx.x & (NCHUNK - 1);
    const int b0    = chunk * ROWS_BLK;

    // ---- phase 1: stage W, hb, cols ----
    for (int i = tid; i < C_ * H_; i += THR) WL[i] = Wt[t * C_ * H_ + i];
    if (tid < H_) hbL[tid] = hb[t * H_ + tid];
    if (tid < C_) colsL[tid] = clusters[t * C_ + tid];
    __syncthreads();

    // ---- phase 2: w2, contiguity ----
    if (tid < C_) {
        float a = vb[t * C_ + tid];
        #pragma unroll
        for (int j = 0; j < H_; ++j) a += WL[tid * H_ + j] * hbL[j];
        w2L[tid] = a;
    }
    if (tid == 0) {
        int ok = (colsL[0] & 3) == 0;
        for (int c = 1; c < C_; ++c) ok &= (colsL[c] == colsL[0] + c);
        contigS = ok;
    }
    __syncthreads();

    // ---- phase 3: G', d, k0 ----
    for (int idx = tid; idx < H_ * H_; idx += THR) {
        const int i = idx / H_, j = idx - i * H_;
        float a = 0.f;
        #pragma unroll
        for (int c = 0; c < C_; ++c) a += WL[c * H_ + i] * WL[c * H_ + j];
        GL[idx] = (i == j) ? a - 2.f : a;
    }
    if (tid < H_) {
        float a = 0.f;
        #pragma unroll
        for (int c = 0; c < C_; ++c) a += w2L[c] * WL[c * H_ + tid];
        dL[tid] = 2.f * a;                       // d = 2 W^T w2
    }
    if (tid == THR - 1) {
        float a = 0.f;
        for (int c = 0; c < C_; ++c) a += w2L[c] * w2L[c];
        k0L = a;
    }
    __syncthreads();

    const int lane = tid & 63;
    const int wid  = tid >> 6;
    const int m    = lane & 15;    // A row / B-D col
    const int quad = lane >> 4;    // k-slice

    // ---- per-wave constant fragments ----
    short8 bw0, bw1;
    float  m2w[8];                 // -2 * w2
    #pragma unroll
    for (int j = 0; j < 8; ++j) {
        const int k = quad * 8 + j;
        bw0[j] = f2bf(WL[k * H_ + m]);                                 // W[c][n]
        bw1[j] = (m < 8) ? f2bf(WL[k * H_ + 16 + m]) : (short)0;       // n=16..23
        m2w[j] = -2.f * w2L[k];
    }
    const float d0 = dL[m];
    const float d1 = (m < 8) ? dL[16 + m] : 0.f;

    const int contig = contigS;
    const int col0   = colsL[0];

    const floatx4 z4 = {0.f, 0.f, 0.f, 0.f};
    floatx4 Mll = z4, Mlh = z4, Mhh = z4;   // M = S^T S accumulators
    floatx4 cs0 = z4, cs1 = z4;             // colsum(S) accumulators (f32)
    float err = 0.f;
    int pA0, pA1, qA0, qA1, pB0, pB1, qB0, qB1;

// one 16-row group: stats + S = X.W (two col-halves), colsum acc, bf16 packs
#define GROUPG(XA, XB, P0, P1, Q0, Q1)                                        \
    {                                                                         \
        const float xv_[8] = {XA.x, XA.y, XA.z, XA.w, XB.x, XB.y, XB.z, XB.w};\
        short8 af;                                                            \
        _Pragma("unroll")                                                     \
        for (int j = 0; j < 8; ++j) {                                         \
            err += xv_[j] * xv_[j] + xv_[j] * m2w[j];                         \
            af[j] = f2bf(xv_[j]);                                             \
        }                                                                     \
        floatx4 S0 = __builtin_amdgcn_mfma_f32_16x16x32_bf16(af, bw0, z4, 0, 0, 0); \
        floatx4 S1 = __builtin_amdgcn_mfma_f32_16x16x32_bf16(af, bw1, z4, 0, 0, 0); \
        cs0 += S0; cs1 += S1;                                                 \
        P0 = pk2bf(S0[0], S0[1]); P1 = pk2bf(S0[2], S0[3]);                   \
        Q0 = pk2bf(S1[0], S1[1]); Q1 = pk2bf(S1[2], S1[3]);                   \
    }

// pair combine: own packs ARE the fragment (chosen row permutation), M += S^T S
#define PAIRC                                                                 \
    {                                                                         \
        intx4 ia, ib;                                                         \
        ia[0] = pA0; ia[1] = pA1; ia[2] = pB0; ia[3] = pB1;                   \
        ib[0] = qA0; ib[1] = qA1; ib[2] = qB0; ib[3] = qB1;                   \
        const short8 SA = __builtin_bit_cast(short8, ia);                     \
        const short8 SB = __builtin_bit_cast(short8, ib);                     \
        Mll = __builtin_amdgcn_mfma_f32_16x16x32_bf16(SA, SA, Mll, 0, 0, 0);  \
        Mlh = __builtin_amdgcn_mfma_f32_16x16x32_bf16(SA, SB, Mlh, 0, 0, 0);  \
        Mhh = __builtin_amdgcn_mfma_f32_16x16x32_bf16(SB, SB, Mhh, 0, 0, 0);  \
    }

    if (contig) {
        // lane covers 32 B of its row; one-group-ahead prefetch
        const float* xbase = x + (size_t)(b0 + wid * 128 + m) * F_ + col0 + quad * 8;
        float4 na = *(const float4*)xbase;
        float4 nc = *(const float4*)(xbase + 4);
        #pragma unroll
        for (int g = 0; g < 8; g += 2) {
            const float4 xa0 = na, xc0 = nc;
            {
                const float* s1 = xbase + (size_t)(g + 1) * 16 * F_;
                na = *(const float4*)s1;
                nc = *(const float4*)(s1 + 4);
            }
            GROUPG(xa0, xc0, pA0, pA1, qA0, qA1)
            const float4 xa1 = na, xc1 = nc;
            if (g < 6) {
                const float* s2 = xbase + (size_t)(g + 2) * 16 * F_;
                na = *(const float4*)s2;
                nc = *(const float4*)(s2 + 4);
            }
            GROUPG(xa1, xc1, pB0, pB1, qB0, qB1)
            PAIRC
        }
    } else {
        for (int g = 0; g < 8; g += 2) {
            const size_t rb0 = (size_t)(b0 + wid * 128 + g * 16 + m) * F_;
            const size_t rb1 = rb0 + (size_t)16 * F_;
            float xf[8], yf[8];
            #pragma unroll
            for (int j = 0; j < 8; ++j) {
                xf[j] = x[rb0 + colsL[quad * 8 + j]];
                yf[j] = x[rb1 + colsL[quad * 8 + j]];
            }
            const float4 xa0 = {xf[0], xf[1], xf[2], xf[3]};
            const float4 xc0 = {xf[4], xf[5], xf[6], xf[7]};
            const float4 xa1 = {yf[0], yf[1], yf[2], yf[3]};
            const float4 xc1 = {yf[4], yf[5], yf[6], yf[7]};
            GROUPG(xa0, xc0, pA0, pA1, qA0, qA1)
            GROUPG(xa1, xc1, pB0, pB1, qB0, qB1)
            PAIRC
        }
    }
#undef GROUPG
#undef PAIRC

    // ---- epilogue: contract M with f32 G' (symmetric: 2x the lo-hi block) ----
    {
        const int i0 = quad * 4;
        float eg = 0.f;
        #pragma unroll
        for (int r = 0; r < 4; ++r) {
            eg += GL[(i0 + r) * H_ + m] * Mll[r];
            if (m < 8) {
                eg += 2.f * GL[(i0 + r) * H_ + 16 + m] * Mlh[r];
                if (i0 + r < 8)
                    eg += GL[(16 + i0 + r) * H_ + 16 + m] * Mhh[r];
            }
        }
        err += eg;
        err += (cs0[0] + cs0[1] + cs0[2] + cs0[3]) * d0;
        if (m < 8) err += (cs1[0] + cs1[1] + cs1[2] + cs1[3]) * d1;
    }

    // ---- reduce: wave shuffle -> block -> one partial per block ----
    #pragma unroll
    for (int off = 32; off > 0; off >>= 1) err += __shfl_down(err, off, 64);
    if (lane == 0) wsum[wid] = err;
    __syncthreads();
    if (tid == 0)
        partial[blockIdx.x] = wsum[0] + wsum[1] + wsum[2] + wsum[3]
                            + (float)ROWS_BLK * k0L;
}

// ---------------------------------------------------------------------------
// Kernel B: sum partials -> tails -> 2 tiny head matmuls. One wave.
// d_out = [ head_out (64) | tails (64) ]
// ---------------------------------------------------------------------------
__global__ __launch_bounds__(64) void kitnet_head(
    const float* __restrict__ partial, const float* __restrict__ Wh,
    const float* __restrict__ hbh, const float* __restrict__ vbh,
    float* __restrict__ out)
{
    __shared__ float tl[T_];
    __shared__ float hhL[HH_];
    const int tid = threadIdx.x;

    float sse = 0.f;
    #pragma unroll 8
    for (int c = 0; c < NCHUNK; ++c) sse += partial[tid * NCHUNK + c];

    const float tail = 0.5f * logf(sse * (1.0f / ((float)B_ * (float)C_)));
    tl[tid] = tail;
    out[T_ + tid] = tail;
    __syncthreads();

    if (tid < HH_) {
        float acc = hbh[tid];
        #pragma unroll 8
        for (int t = 0; t < T_; ++t) acc += tl[t] * Wh[t * HH_ + tid];
        hhL[tid] = acc;
    }
    __syncthreads();

    float ho = vbh[tid];
    #pragma unroll 8
    for (int j = 0; j < HH_; ++j) ho += hhL[j] * Wh[tid * HH_ + j];
    out[tid] = ho;
}

extern "C" void kernel_launch(void* const* d_in, const int* in_sizes, int n_in,
                              void* d_out, int out_size, void* d_ws, size_t ws_size,
                              hipStream_t stream)
{
    const float* x        = (const float*)d_in[0];
    const int*   clusters = (const int*)  d_in[1];
    const float* Wt       = (const float*)d_in[2];
    const float* hb       = (const float*)d_in[3];
    const float* vb       = (const float*)d_in[4];
    const float* Wh       = (const float*)d_in[5];
    const float* hbh      = (const float*)d_in[6];
    const float* vbh      = (const float*)d_in[7];
    float* out     = (float*)d_out;
    float* partial = (float*)d_ws;   // GRID_ floats; every slot written each call

    kitnet_main<<<dim3(GRID_), dim3(THR), 0, stream>>>(x, clusters, Wt, hb, vb, partial);
    kitnet_head<<<dim3(1), dim3(64), 0, stream>>>(partial, Wh, hbh, vbh, out);
}